// Round 10
// baseline (75.660 us; speedup 1.0000x reference)
//
#include <hip/hip_runtime.h>
#include <hip/hip_bf16.h>
#include <math.h>

// Problem constants
#define Bb 4
#define Nn 512
#define Mm 64
#define Ff 256
#define Qq 16
#define Hh 8
#define Rr 32
#define FFNH 512
#define ROWS (Bb*Nn)          // 2048
#define KIN (Ff+Qq)           // 272
#define KINP 288              // padded to 9*32
#define KOUT (2*Ff+Rr)        // 544 = 17*32

typedef short short8 __attribute__((ext_vector_type(8)));
typedef unsigned short ushort8 __attribute__((ext_vector_type(8)));
typedef float f32x4 __attribute__((ext_vector_type(4)));

__device__ inline unsigned short f2b(float f) {
    union { float f; unsigned u; } c; c.f = f;
    unsigned r = c.u + 0x7fffu + ((c.u >> 16) & 1u);
    return (unsigned short)(r >> 16);
}
__device__ inline float b2f(unsigned short u) {
    union { unsigned u; float f; } c; c.u = ((unsigned)u) << 16;
    return c.f;
}

// arena segments (ushort offsets)
#define OFF_CENTER 0
#define OFF_WQKV   (OFF_CENTER + ROWS*KINP)            // 589824
#define OFF_WOUT   (OFF_WQKV + 768*KINP)               // 811008
#define OFF_WF1    (OFF_WOUT + Ff*KOUT)                // 950272
#define OFF_WF2    (OFF_WF1 + FFNH*Ff)                 // 1081344
#define OFF_U      (OFF_WF2 + Ff*FFNH)                 // 1212416
#define OFF_XB     (OFF_U + ROWS*KOUT)                 // 2326528 (unused now)
#define OFF_FFH    (OFF_XB + ROWS*Ff)                  // 2850816
#define OFF_QKVB   (OFF_FFH + ROWS*FFNH)               // 3899392
#define CONV_TOTAL OFF_U                               // 1212416
#define CONV_BLK4  (CONV_TOTAL/1024)                   // 1184 (4 elems/thread)
#define A2U_BLK4   (ROWS*Ff/1024)                      // 512
#define MSK_BLK16  (Bb*Nn*Mm/(256*16))                 // 32

// ---------------------------------------------------------------- prep (vectorized): convert + U[:, :256]=bf16(a) + detect mask
__global__ __launch_bounds__(256) void prep(const float* __restrict__ a,
                                            const float* __restrict__ ch,
                                            const float* __restrict__ Wq,
                                            const float* __restrict__ Wk,
                                            const float* __restrict__ Wv,
                                            const float* __restrict__ Wout,
                                            const float* __restrict__ Wf1,
                                            const float* __restrict__ Wf2,
                                            const unsigned char* __restrict__ mask,
                                            int* __restrict__ flag,
                                            unsigned short* __restrict__ arena) {
    int bid = blockIdx.x, tid = threadIdx.x;
    if (bid < CONV_BLK4) {
        int i = (bid * 256 + tid) * 4;     // aligned 4-group; all segment boundaries are multiples of 4
        float4 v4 = {0.f, 0.f, 0.f, 0.f};
        if (i < OFF_WQKV) {
            int row = i / KINP, c = i - row * KINP;   // KINP%4==0 -> group within one row
            if (c < Ff)       v4 = *reinterpret_cast<const float4*>(a  + (size_t)row * Ff + c);
            else if (c < KIN) v4 = *reinterpret_cast<const float4*>(ch + (size_t)row * Qq + (c - Ff));
        } else if (i < OFF_WOUT) {
            int j = i - OFF_WQKV;
            int n = j / KINP, c = j - n * KINP;
            const float* W = n < 256 ? Wq : (n < 512 ? Wk : Wv);
            int nr = n & 255;
            if (c < KIN) v4 = *reinterpret_cast<const float4*>(W + (size_t)nr * KIN + c);
        } else if (i < OFF_WF1) {
            v4 = *reinterpret_cast<const float4*>(Wout + (i - OFF_WOUT));
        } else if (i < OFF_WF2) {
            v4 = *reinterpret_cast<const float4*>(Wf1 + (i - OFF_WF1));
        } else {
            v4 = *reinterpret_cast<const float4*>(Wf2 + (i - OFF_WF2));
        }
        ushort4 u;
        u.x = f2b(v4.x); u.y = f2b(v4.y); u.z = f2b(v4.z); u.w = f2b(v4.w);
        *reinterpret_cast<ushort4*>(arena + i) = u;
    } else if (bid < CONV_BLK4 + A2U_BLK4) {
        int j = ((bid - CONV_BLK4) * 256 + tid) * 4;
        int row = j >> 8, col = j & 255;
        float4 v4 = *reinterpret_cast<const float4*>(a + j);
        ushort4 u;
        u.x = f2b(v4.x); u.y = f2b(v4.y); u.z = f2b(v4.z); u.w = f2b(v4.w);
        *reinterpret_cast<ushort4*>(arena + OFF_U + (size_t)row * KOUT + col) = u;
    } else {
        // mask scan, 16 bytes/thread: bytes at (i%4)!=0 nonzero => bool layout
        int i = ((bid - CONV_BLK4 - A2U_BLK4) * 256 + tid) * 4;   // uint index
        const uint4 v = reinterpret_cast<const uint4*>(mask)[i >> 2];
        unsigned m = (v.x | v.y | v.z | v.w) & 0xFFFFFF00u;
        if (m) *flag = 1;
    }
}

// ---------------------------------------------------------------- MFMA GEMM: C = A(bf16) @ W(bf16)^T
// MODE 0: fp32 out (split-K partials via blockIdx.z, no bias)
// MODE 1: bias per 256-col block -> bf16 out Cb (QKV)
template<int KT, int SPLIT, int MODE>
__global__ __launch_bounds__(256) void gemm_mfma(const unsigned short* __restrict__ Ab, int lda,
                                                 const unsigned short* __restrict__ Wb, int ldw,
                                                 const float* __restrict__ b0,
                                                 const float* __restrict__ b1,
                                                 const float* __restrict__ b2,
                                                 float* __restrict__ C,
                                                 unsigned short* __restrict__ Cb,
                                                 int ldc, size_t pstride) {
    __shared__ unsigned short As[2][64][32];
    __shared__ unsigned short Bs[2][64][32];
    int tid = threadIdx.x;
    int colbase = blockIdx.x * 64;
    int rowbase = blockIdx.y * 64;
    constexpr int TPER = (KT + SPLIT - 1) / SPLIT;
    int t0 = blockIdx.z * TPER;
    int NL = KT - t0; if (NL > TPER) NL = TPER;

    int sr = tid >> 2, sl = tid & 3;
    const unsigned short* Ap = Ab + (size_t)(rowbase + sr) * lda + sl * 8;
    const unsigned short* Wp = Wb + (size_t)(colbase + sr) * ldw + sl * 8;
    int ssw = (sl ^ (sr & 3)) * 8;

    int wave = tid >> 6, lane = tid & 63;
    int wr = (wave >> 1) * 32, wc = (wave & 1) * 32;
    int lrow = lane & 15;
    int kslot = lane >> 4;
    int sp = (kslot ^ (lane & 3)) * 8;

    uint4 av, wv;
    auto prefetch = [&](int t) {
        av = *reinterpret_cast<const uint4*>(Ap + (size_t)t * 32);
        wv = *reinterpret_cast<const uint4*>(Wp + (size_t)t * 32);
    };
    auto writeLDS = [&](int buf) {
        *reinterpret_cast<uint4*>(&As[buf][sr][ssw]) = av;
        *reinterpret_cast<uint4*>(&Bs[buf][sr][ssw]) = wv;
    };

    f32x4 acc[2][2] = {};
    prefetch(t0);
    writeLDS(0);
    __syncthreads();
    for (int tt = 0; tt < NL; ++tt) {
        if (tt + 1 < NL) prefetch(t0 + tt + 1);
        int buf = tt & 1;
        short8 a0 = *reinterpret_cast<const short8*>(&As[buf][wr + lrow][sp]);
        short8 a1 = *reinterpret_cast<const short8*>(&As[buf][wr + 16 + lrow][sp]);
        short8 bv0 = *reinterpret_cast<const short8*>(&Bs[buf][wc + lrow][sp]);
        short8 bv1 = *reinterpret_cast<const short8*>(&Bs[buf][wc + 16 + lrow][sp]);
        acc[0][0] = __builtin_amdgcn_mfma_f32_16x16x32_bf16(a0, bv0, acc[0][0], 0, 0, 0);
        acc[0][1] = __builtin_amdgcn_mfma_f32_16x16x32_bf16(a0, bv1, acc[0][1], 0, 0, 0);
        acc[1][0] = __builtin_amdgcn_mfma_f32_16x16x32_bf16(a1, bv0, acc[1][0], 0, 0, 0);
        acc[1][1] = __builtin_amdgcn_mfma_f32_16x16x32_bf16(a1, bv1, acc[1][1], 0, 0, 0);
        if (tt + 1 < NL) {
            writeLDS((tt + 1) & 1);
            __syncthreads();
        }
    }

    const float* bias = b0;
    if (MODE == 1) {
        int sel = colbase >> 8;
        bias = sel == 0 ? b0 : (sel == 1 ? b1 : b2);
    }
    int colq = (colbase & 255);
    float* Cp = (MODE == 0) ? C + (size_t)blockIdx.z * pstride : C;
    #pragma unroll
    for (int fr = 0; fr < 2; ++fr) {
        #pragma unroll
        for (int fc = 0; fc < 2; ++fc) {
            int coll = wc + fc * 16 + (lane & 15);
            int col = colbase + coll;
            #pragma unroll
            for (int i = 0; i < 4; ++i) {
                int row = rowbase + wr + fr * 16 + (lane >> 4) * 4 + i;
                float v = acc[fr][fc][i];
                if (MODE == 0) {
                    Cp[(size_t)row * ldc + col] = v;
                } else {
                    Cb[(size_t)row * ldc + col] = f2b(v + bias[colq + coll]);
                }
            }
        }
    }
}

// ---------------------------------------------------------------- attention: bf16 K/V, double-buffered LDS tiles
__global__ __launch_bounds__(256) void attn_kernel(const unsigned short* __restrict__ QKV,
                                                   const int* __restrict__ idx_j,
                                                   const float* __restrict__ d_ij,
                                                   const void* __restrict__ mask,
                                                   const float* __restrict__ shifts,
                                                   const float* __restrict__ Wrb,
                                                   const float* __restrict__ brb,
                                                   const int* __restrict__ flag,
                                                   unsigned short* __restrict__ Ub) {
    __shared__ unsigned short Kt[2][16][280];
    __shared__ float rad[Mm][36];
    __shared__ float att[Hh][Mm];
    __shared__ float attbar[Mm];
    __shared__ int   jl[Mm];
    __shared__ float dv[Mm];
    __shared__ int   maskf[Mm];
    __shared__ float shs[Rr];

    int row = blockIdx.x;
    int b = row >> 9;
    int tid = threadIdx.x;
    bool boolmask = (*flag != 0);

    if (tid < Mm) jl[tid] = idx_j[row * Mm + tid];
    else if (tid < 128) { int m = tid - 64; dv[m] = d_ij[row * Mm + m]; }
    else if (tid < 160) shs[tid - 128] = shifts[tid - 128];
    else if (tid >= 192) {
        int m = tid - 192;
        maskf[m] = boolmask ? (int)((const unsigned char*)mask)[row * Mm + m]
                            : ((const int*)mask)[row * Mm + m];
    }

    int half = tid & 1;
    int p = tid >> 1;
    int hh = p >> 4;
    int ml = p & 15;
    float qf[16];
    {
        const unsigned short* qrow = QKV + (size_t)row * 768 + hh * 32 + half * 16;
        ushort8 q0 = *reinterpret_cast<const ushort8*>(qrow);
        ushort8 q1 = *reinterpret_cast<const ushort8*>(qrow + 8);
        #pragma unroll
        for (int i = 0; i < 8; ++i) { qf[i] = b2f(q0[i]); qf[8 + i] = b2f(q1[i]); }
    }
    float4 wreg[4];
    #pragma unroll
    for (int c = 0; c < 4; ++c)
        wreg[c] = *reinterpret_cast<const float4*>(Wrb + hh * Rr + half * 16 + c * 4);
    float brbh = brb[hh];
    __syncthreads();

    auto stage = [&](int t, int seg, int buf) {
        #pragma unroll
        for (int q = 0; q < 2; ++q) {
            int chunk = q * 256 + tid;
            int r = chunk >> 5, s = chunk & 31;
            int j = jl[t * 16 + r];
            const uint4* src = reinterpret_cast<const uint4*>(QKV + (size_t)(b * Nn + j) * 768 + seg);
            uint4 v = src[s];
            *reinterpret_cast<uint4*>(&Kt[buf][r][s * 8]) = v;
        }
    };

    #pragma unroll
    for (int it = 0; it < 8; ++it) {
        int i = tid + it * 256;
        int m = i >> 5, r = i & 31;
        float t = dv[m] - shs[r];
        rad[m][r] = expf(-4.0f * t * t);
    }
    stage(0, 256, 0);
    __syncthreads();

    for (int t = 0; t < 4; ++t) {
        if (t < 3) stage(t + 1, 256, (t + 1) & 1);
        int buf = t & 1;
        const unsigned short* kr = &Kt[buf][ml][hh * 32 + half * 16];
        ushort8 k0 = *reinterpret_cast<const ushort8*>(kr);
        ushort8 k1 = *reinterpret_cast<const ushort8*>(kr + 8);
        float accK = 0.f;
        #pragma unroll
        for (int i = 0; i < 8; ++i) accK = fmaf(qf[i], b2f(k0[i]), accK);
        #pragma unroll
        for (int i = 0; i < 8; ++i) accK = fmaf(qf[8 + i], b2f(k1[i]), accK);
        float accR = 0.f;
        #pragma unroll
        for (int c = 0; c < 4; ++c) {
            float4 rv = *reinterpret_cast<const float4*>(&rad[t * 16 + ml][half * 16 + c * 4]);
            accR += wreg[c].x * rv.x + wreg[c].y * rv.y + wreg[c].z * rv.z + wreg[c].w * rv.w;
        }
        float tv = accK * 0.17677669529663687f + accR;
        tv += __shfl_xor(tv, 1);
        if (!half) {
            int m = t * 16 + ml;
            att[hh][m] = maskf[m] ? -INFINITY : (tv + brbh);
        }
        __syncthreads();
    }

    {
        int h = tid >> 5, l = tid & 31;
        float s0 = att[h][l], s1 = att[h][l + 32];
        float mx = fmaxf(s0, s1);
        #pragma unroll
        for (int off = 16; off; off >>= 1) mx = fmaxf(mx, __shfl_xor(mx, off, 32));
        float e0 = 0.f, e1 = 0.f;
        if (mx != -INFINITY) {
            e0 = expf(s0 - mx);
            e1 = expf(s1 - mx);
        }
        float sm = e0 + e1;
        #pragma unroll
        for (int off = 16; off; off >>= 1) sm += __shfl_xor(sm, off, 32);
        float inv = sm > 0.f ? 1.f / sm : 0.f;
        att[h][l] = e0 * inv;
        att[h][l + 32] = e1 * inv;
    }
    stage(0, 512, 0);
    __syncthreads();

    float ctx = 0.f;
    int h2 = tid >> 5, d0 = tid & 31;
    for (int t = 0; t < 4; ++t) {
        if (t < 3) stage(t + 1, 512, (t + 1) & 1);
        int buf = t & 1;
        #pragma unroll
        for (int m = 0; m < 16; ++m)
            ctx = fmaf(att[h2][t * 16 + m], b2f(Kt[buf][m][h2 * 32 + d0]), ctx);
        if (t == 0 && tid < Mm) {
            float sv = 0.f;
            #pragma unroll
            for (int h = 0; h < Hh; ++h) sv += att[h][tid];
            attbar[tid] = sv * 0.125f;
        }
        __syncthreads();
    }

    Ub[(size_t)row * KOUT + Ff + tid] = f2b(ctx);

    if (tid < 64) {
        int g = tid >> 1;
        float acc = 0.f;
        #pragma unroll
        for (int i = 0; i < 32; ++i) {
            int m = half * 32 + i;
            acc = fmaf(attbar[m], rad[m][g], acc);
        }
        acc += __shfl_xor(acc, 1);
        if (!half) Ub[(size_t)row * KOUT + 2 * Ff + g] = f2b(acc);
    }
}

// ---------------------------------------------------------------- ffn1_ln: LN1(a+bout+partials) -> LDS A-tile -> FFN1 GEMM + GELU
// grid (8, 32), 256 threads. col-block 0 also writes xbuf (LN1 output, fp32) for the final residual.
__global__ __launch_bounds__(256) void ffn1_ln(const float* __restrict__ part, size_t pstride,
                                               const float* __restrict__ a,
                                               const float* __restrict__ bout,
                                               const float* __restrict__ g1,
                                               const float* __restrict__ b1,
                                               const unsigned short* __restrict__ Wf1b,
                                               const float* __restrict__ bf1,
                                               float* __restrict__ xbuf,
                                               unsigned short* __restrict__ ffhb) {
    __shared__ unsigned short Af[64][264];    // LN1 output bf16; 264 pad -> 33 16B-granules/row (odd) => conflict-free b128
    __shared__ unsigned short Bs[2][64][32];

    int tid = threadIdx.x;
    int wave = tid >> 6, lane = tid & 63;
    int rowbase = blockIdx.y * 64;
    int colbase = blockIdx.x * 64;

    // B tile 0 prefetch (overlaps with LN phase)
    int sr = tid >> 2, sl = tid & 3;
    const unsigned short* Wp = Wf1b + (size_t)(colbase + sr) * Ff + sl * 8;
    int ssw = (sl ^ (sr & 3)) * 8;
    uint4 wv = *reinterpret_cast<const uint4*>(Wp);

    // ---- LN phase: wave handles 16 rows; lane covers cols {l, l+64, l+128, l+192}
    {
        float bo[4], gg[4], bb[4];
        #pragma unroll
        for (int j = 0; j < 4; ++j) {
            int c = lane + 64 * j;
            bo[j] = bout[c]; gg[j] = g1[c]; bb[j] = b1[c];
        }
        for (int rr = 0; rr < 16; ++rr) {
            int r = wave * 16 + rr;
            size_t off = (size_t)(rowbase + r) * Ff;
            float v[4]; float sm = 0.f;
            #pragma unroll
            for (int j = 0; j < 4; ++j) {
                int c = lane + 64 * j;
                v[j] = a[off + c] + bo[j] + part[off + c] + part[pstride + off + c];
                sm += v[j];
            }
            #pragma unroll
            for (int o = 32; o; o >>= 1) sm += __shfl_xor(sm, o, 64);
            float mu = sm * (1.f / Ff);
            float s2 = 0.f;
            #pragma unroll
            for (int j = 0; j < 4; ++j) { float d = v[j] - mu; s2 += d * d; }
            #pragma unroll
            for (int o = 32; o; o >>= 1) s2 += __shfl_xor(s2, o, 64);
            float inv = rsqrtf(s2 * (1.f / Ff) + 1e-5f);
            #pragma unroll
            for (int j = 0; j < 4; ++j) {
                int c = lane + 64 * j;
                float res = (v[j] - mu) * inv * gg[j] + bb[j];
                Af[r][c] = f2b(res);
                if (blockIdx.x == 0) xbuf[off + c] = res;
            }
        }
    }
    // write B tile 0, then one barrier covers Af + Bs[0]
    *reinterpret_cast<uint4*>(&Bs[0][sr][ssw]) = wv;
    __syncthreads();

    // ---- GEMM: 64x64 out, K=256 (8 tiles), B double-buffered, A from Af (plain layout)
    int wr = (wave >> 1) * 32, wc = (wave & 1) * 32;
    int lrow = lane & 15;
    int kslot = lane >> 4;
    int sp = (kslot ^ (lane & 3)) * 8;

    f32x4 acc[2][2] = {};
    for (int tt = 0; tt < 8; ++tt) {
        if (tt + 1 < 8) wv = *reinterpret_cast<const uint4*>(Wp + (size_t)(tt + 1) * 32);
        int buf = tt & 1;
        short8 a0 = *reinterpret_cast<const short8*>(&Af[wr + lrow][tt * 32 + kslot * 8]);
        short8 a1 = *reinterpret_cast<const short8*>(&Af[wr + 16 + lrow][tt * 32 + kslot * 8]);
        short8 bv0 = *reinterpret_cast<const short8*>(&Bs[buf][wc + lrow][sp]);
        short8 bv1 = *reinterpret_cast<const short8*>(&Bs[buf][wc + 16 + lrow][sp]);
        acc[0][0] = __builtin_amdgcn_mfma_f32_16x16x32_bf16(a0, bv0, acc[0][0], 0, 0, 0);
        acc[0][1] = __builtin_amdgcn_mfma_f32_16x16x32_bf16(a0, bv1, acc[0][1], 0, 0, 0);
        acc[1][0] = __builtin_amdgcn_mfma_f32_16x16x32_bf16(a1, bv0, acc[1][0], 0, 0, 0);
        acc[1][1] = __builtin_amdgcn_mfma_f32_16x16x32_bf16(a1, bv1, acc[1][1], 0, 0, 0);
        if (tt + 1 < 8) {
            *reinterpret_cast<uint4*>(&Bs[(tt + 1) & 1][sr][ssw]) = wv;
            __syncthreads();
        }
    }

    // ---- epilogue: bias + exact GELU -> bf16 ffhb (ldc = FFNH)
    #pragma unroll
    for (int fr = 0; fr < 2; ++fr) {
        #pragma unroll
        for (int fc = 0; fc < 2; ++fc) {
            int col = colbase + wc + fc * 16 + (lane & 15);
            float badd = bf1[col];
            #pragma unroll
            for (int i = 0; i < 4; ++i) {
                int row = rowbase + wr + fr * 16 + (lane >> 4) * 4 + i;
                float v = acc[fr][fc][i] + badd;
                v = 0.5f * v * (1.0f + erff(v * 0.70710678118654752f));
                ffhb[(size_t)row * FFNH + col] = f2b(v);
            }
        }
    }
}

// ---------------------------------------------------------------- residual + bias + 2 partials + LN (wave per row)
__global__ __launch_bounds__(256) void add_ln_c(const float* __restrict__ x0,
                                                const float* __restrict__ part, size_t pstride,
                                                const float* __restrict__ bias,
                                                const float* __restrict__ g,
                                                const float* __restrict__ be,
                                                float* __restrict__ outp) {
    int tid = threadIdx.x;
    int wave = tid >> 6, lane = tid & 63;
    int row = blockIdx.x * 4 + wave;
    size_t off = (size_t)row * Ff + lane * 4;
    float4 v = *reinterpret_cast<const float4*>(x0 + off);
    float4 bb = *reinterpret_cast<const float4*>(bias + lane * 4);
    v.x += bb.x; v.y += bb.y; v.z += bb.z; v.w += bb.w;
    #pragma unroll
    for (int s = 0; s < 2; ++s) {
        float4 p = *reinterpret_cast<const float4*>(part + (size_t)s * pstride + off);
        v.x += p.x; v.y += p.y; v.z += p.z; v.w += p.w;
    }
    float sm = v.x + v.y + v.z + v.w;
    #pragma unroll
    for (int o = 32; o; o >>= 1) sm += __shfl_xor(sm, o, 64);
    float mu = sm * (1.f / Ff);
    float4 c = {v.x - mu, v.y - mu, v.z - mu, v.w - mu};
    float s2 = c.x * c.x + c.y * c.y + c.z * c.z + c.w * c.w;
    #pragma unroll
    for (int o = 32; o; o >>= 1) s2 += __shfl_xor(s2, o, 64);
    float inv = rsqrtf(s2 * (1.f / Ff) + 1e-5f);
    float4 gg = *reinterpret_cast<const float4*>(g + lane * 4);
    float4 ee = *reinterpret_cast<const float4*>(be + lane * 4);
    float4 r;
    r.x = c.x * inv * gg.x + ee.x;
    r.y = c.y * inv * gg.y + ee.y;
    r.z = c.z * inv * gg.z + ee.z;
    r.w = c.w * inv * gg.w + ee.w;
    *reinterpret_cast<float4*>(outp + off) = r;
}

// ---------------------------------------------------------------- launch
extern "C" void kernel_launch(void* const* d_in, const int* in_sizes, int n_in,
                              void* d_out, int out_size, void* d_ws, size_t ws_size,
                              hipStream_t stream) {
    const float* a       = (const float*)d_in[0];
    const float* charges = (const float*)d_in[1];
    const int*   idx_j   = (const int*)  d_in[2];
    const float* d_ij    = (const float*)d_in[3];
    const void*  mask    =               d_in[4];
    const float* shifts  = (const float*)d_in[5];
    const float* Wq   = (const float*)d_in[6];  const float* bq   = (const float*)d_in[7];
    const float* Wk   = (const float*)d_in[8];  const float* bk   = (const float*)d_in[9];
    const float* Wv   = (const float*)d_in[10]; const float* bv   = (const float*)d_in[11];
    const float* Wrb  = (const float*)d_in[12]; const float* brb  = (const float*)d_in[13];
    const float* Wout = (const float*)d_in[14]; const float* bout = (const float*)d_in[15];
    const float* g1   = (const float*)d_in[16]; const float* b1   = (const float*)d_in[17];
    const float* g2   = (const float*)d_in[18]; const float* b2   = (const float*)d_in[19];
    const float* Wf1  = (const float*)d_in[20]; const float* bf1  = (const float*)d_in[21];
    const float* Wf2  = (const float*)d_in[22]; const float* bf2  = (const float*)d_in[23];
    float* outp = (float*)d_out;

    float* ws   = (float*)d_ws;
    int*   flag = (int*)d_ws;
    // ws layout (floats): flag(1024) | part (1,048,576) | xbuf (524,288) | bf16 arena
    float* part = ws + 1024;
    float* xbuf = part + 1048576;
    unsigned short* arena = (unsigned short*)(xbuf + 524288);
    unsigned short* centerb = arena + OFF_CENTER;
    unsigned short* Wqkvb   = arena + OFF_WQKV;
    unsigned short* Woutb   = arena + OFF_WOUT;
    unsigned short* Wf1b    = arena + OFF_WF1;
    unsigned short* Wf2b    = arena + OFF_WF2;
    unsigned short* Ub      = arena + OFF_U;
    unsigned short* ffhb    = arena + OFF_FFH;
    unsigned short* QKVB16  = arena + OFF_QKVB;

    hipMemsetAsync(flag, 0, sizeof(int), stream);
    prep<<<CONV_BLK4 + A2U_BLK4 + MSK_BLK16, 256, 0, stream>>>(
        a, charges, Wq, Wk, Wv, Wout, Wf1, Wf2, (const unsigned char*)mask, flag, arena);

    // QKV: [2048 x 768], K=288 (9 tiles), bias fused, bf16 out
    gemm_mfma<9, 1, 1><<<dim3(12, 32, 1), 256, 0, stream>>>(
        centerb, KINP, Wqkvb, KINP, bq, bk, bv, nullptr, QKVB16, 768, 0);

    attn_kernel<<<ROWS, 256, 0, stream>>>(QKVB16, idx_j, d_ij, mask, shifts, Wrb, brb, flag, Ub);

    // Wout: [2048 x 256], K=544 (17 tiles), split 2 -> partials
    gemm_mfma<17, 2, 0><<<dim3(4, 32, 2), 256, 0, stream>>>(
        Ub, KOUT, Woutb, KOUT, nullptr, nullptr, nullptr, part, nullptr, Ff, (size_t)ROWS * Ff);

    // LN1 + FFN1 + GELU fused
    ffn1_ln<<<dim3(8, 32), 256, 0, stream>>>(
        part, (size_t)ROWS * Ff, a, bout, g1, b1, Wf1b, bf1, xbuf, ffhb);

    // FFN2: [2048 x 256], K=512 (16 tiles), split 2
    gemm_mfma<16, 2, 0><<<dim3(4, 32, 2), 256, 0, stream>>>(
        ffhb, FFNH, Wf2b, FFNH, nullptr, nullptr, nullptr, part, nullptr, Ff, (size_t)ROWS * Ff);
    add_ln_c<<<ROWS / 4, 256, 0, stream>>>(xbuf, part, (size_t)ROWS * Ff, bf2, g2, b2, outp);
}

// Round 11
// 64.278 us; speedup vs baseline: 1.1771x; 1.1771x over previous
//
#include <hip/hip_runtime.h>
#include <hip/hip_bf16.h>
#include <math.h>

// Problem constants
#define Bb 4
#define Nn 512
#define Mm 64
#define Ff 256
#define Qq 16
#define Hh 8
#define Rr 32
#define FFNH 512
#define ROWS (Bb*Nn)          // 2048
#define KIN (Ff+Qq)           // 272
#define KINP 288              // padded to 9*32
#define KOUT (2*Ff+Rr)        // 544 = 17*32

typedef short short8 __attribute__((ext_vector_type(8)));
typedef unsigned short ushort8 __attribute__((ext_vector_type(8)));
typedef float f32x4 __attribute__((ext_vector_type(4)));

__device__ inline unsigned short f2b(float f) {
    union { float f; unsigned u; } c; c.f = f;
    unsigned r = c.u + 0x7fffu + ((c.u >> 16) & 1u);
    return (unsigned short)(r >> 16);
}
__device__ inline float b2f(unsigned short u) {
    union { unsigned u; float f; } c; c.u = ((unsigned)u) << 16;
    return c.f;
}

// arena segments (ushort offsets)
#define OFF_CENTER 0
#define OFF_WQKV   (OFF_CENTER + ROWS*KINP)            // 589824
#define OFF_WOUT   (OFF_WQKV + 768*KINP)               // 811008
#define OFF_WF1    (OFF_WOUT + Ff*KOUT)                // 950272
#define OFF_WF2    (OFF_WF1 + FFNH*Ff)                 // 1081344
#define OFF_U      (OFF_WF2 + Ff*FFNH)                 // 1212416
#define OFF_XB     (OFF_U + ROWS*KOUT)                 // 2326528
#define OFF_FFH    (OFF_XB + ROWS*Ff)                  // 2850816
#define OFF_QKVB   (OFF_FFH + ROWS*FFNH)               // 3899392
#define CONV_TOTAL OFF_U                               // 1212416
#define CONV_BLK4  (CONV_TOTAL/1024)                   // 1184 (4 elems/thread)
#define A2U_BLK4   (ROWS*Ff/1024)                      // 512
#define MSK_BLK16  (Bb*Nn*Mm/(256*16))                 // 32

// ---------------------------------------------------------------- prep (vectorized): convert + U[:, :256]=bf16(a) + detect mask
__global__ __launch_bounds__(256) void prep(const float* __restrict__ a,
                                            const float* __restrict__ ch,
                                            const float* __restrict__ Wq,
                                            const float* __restrict__ Wk,
                                            const float* __restrict__ Wv,
                                            const float* __restrict__ Wout,
                                            const float* __restrict__ Wf1,
                                            const float* __restrict__ Wf2,
                                            const unsigned char* __restrict__ mask,
                                            int* __restrict__ flag,
                                            unsigned short* __restrict__ arena) {
    int bid = blockIdx.x, tid = threadIdx.x;
    if (bid < CONV_BLK4) {
        int i = (bid * 256 + tid) * 4;     // aligned 4-group; all segment boundaries are multiples of 4
        float4 v4 = {0.f, 0.f, 0.f, 0.f};
        if (i < OFF_WQKV) {
            int row = i / KINP, c = i - row * KINP;   // KINP%4==0 -> group within one row
            if (c < Ff)       v4 = *reinterpret_cast<const float4*>(a  + (size_t)row * Ff + c);
            else if (c < KIN) v4 = *reinterpret_cast<const float4*>(ch + (size_t)row * Qq + (c - Ff));
        } else if (i < OFF_WOUT) {
            int j = i - OFF_WQKV;
            int n = j / KINP, c = j - n * KINP;
            const float* W = n < 256 ? Wq : (n < 512 ? Wk : Wv);
            int nr = n & 255;
            if (c < KIN) v4 = *reinterpret_cast<const float4*>(W + (size_t)nr * KIN + c);
        } else if (i < OFF_WF1) {
            v4 = *reinterpret_cast<const float4*>(Wout + (i - OFF_WOUT));
        } else if (i < OFF_WF2) {
            v4 = *reinterpret_cast<const float4*>(Wf1 + (i - OFF_WF1));
        } else {
            v4 = *reinterpret_cast<const float4*>(Wf2 + (i - OFF_WF2));
        }
        ushort4 u;
        u.x = f2b(v4.x); u.y = f2b(v4.y); u.z = f2b(v4.z); u.w = f2b(v4.w);
        *reinterpret_cast<ushort4*>(arena + i) = u;
    } else if (bid < CONV_BLK4 + A2U_BLK4) {
        int j = ((bid - CONV_BLK4) * 256 + tid) * 4;
        int row = j >> 8, col = j & 255;
        float4 v4 = *reinterpret_cast<const float4*>(a + j);
        ushort4 u;
        u.x = f2b(v4.x); u.y = f2b(v4.y); u.z = f2b(v4.z); u.w = f2b(v4.w);
        *reinterpret_cast<ushort4*>(arena + OFF_U + (size_t)row * KOUT + col) = u;
    } else {
        // mask scan, 16 bytes/thread: bytes at (i%4)!=0 nonzero => bool layout
        int i = ((bid - CONV_BLK4 - A2U_BLK4) * 256 + tid) * 4;   // uint index
        const uint4 v = reinterpret_cast<const uint4*>(mask)[i >> 2];
        unsigned m = (v.x | v.y | v.z | v.w) & 0xFFFFFF00u;
        if (m) *flag = 1;
    }
}

// ---------------------------------------------------------------- MFMA GEMM: C = A(bf16) @ W(bf16)^T
// MODE 0: fp32 out (split-K partials via blockIdx.z, no bias)
// MODE 1: bias per 256-col block -> bf16 out Cb (QKV)
// MODE 2: bias b0 + exact GELU -> bf16 out Cb
template<int KT, int SPLIT, int MODE>
__global__ __launch_bounds__(256) void gemm_mfma(const unsigned short* __restrict__ Ab, int lda,
                                                 const unsigned short* __restrict__ Wb, int ldw,
                                                 const float* __restrict__ b0,
                                                 const float* __restrict__ b1,
                                                 const float* __restrict__ b2,
                                                 float* __restrict__ C,
                                                 unsigned short* __restrict__ Cb,
                                                 int ldc, size_t pstride) {
    __shared__ unsigned short As[2][64][32];
    __shared__ unsigned short Bs[2][64][32];
    int tid = threadIdx.x;
    int colbase = blockIdx.x * 64;
    int rowbase = blockIdx.y * 64;
    constexpr int TPER = (KT + SPLIT - 1) / SPLIT;
    int t0 = blockIdx.z * TPER;
    int NL = KT - t0; if (NL > TPER) NL = TPER;

    int sr = tid >> 2, sl = tid & 3;
    const unsigned short* Ap = Ab + (size_t)(rowbase + sr) * lda + sl * 8;
    const unsigned short* Wp = Wb + (size_t)(colbase + sr) * ldw + sl * 8;
    int ssw = (sl ^ (sr & 3)) * 8;

    int wave = tid >> 6, lane = tid & 63;
    int wr = (wave >> 1) * 32, wc = (wave & 1) * 32;
    int lrow = lane & 15;
    int kslot = lane >> 4;
    int sp = (kslot ^ (lane & 3)) * 8;

    uint4 av, wv;
    auto prefetch = [&](int t) {
        av = *reinterpret_cast<const uint4*>(Ap + (size_t)t * 32);
        wv = *reinterpret_cast<const uint4*>(Wp + (size_t)t * 32);
    };
    auto writeLDS = [&](int buf) {
        *reinterpret_cast<uint4*>(&As[buf][sr][ssw]) = av;
        *reinterpret_cast<uint4*>(&Bs[buf][sr][ssw]) = wv;
    };

    f32x4 acc[2][2] = {};
    prefetch(t0);
    writeLDS(0);
    __syncthreads();
    for (int tt = 0; tt < NL; ++tt) {
        if (tt + 1 < NL) prefetch(t0 + tt + 1);
        int buf = tt & 1;
        short8 a0 = *reinterpret_cast<const short8*>(&As[buf][wr + lrow][sp]);
        short8 a1 = *reinterpret_cast<const short8*>(&As[buf][wr + 16 + lrow][sp]);
        short8 bv0 = *reinterpret_cast<const short8*>(&Bs[buf][wc + lrow][sp]);
        short8 bv1 = *reinterpret_cast<const short8*>(&Bs[buf][wc + 16 + lrow][sp]);
        acc[0][0] = __builtin_amdgcn_mfma_f32_16x16x32_bf16(a0, bv0, acc[0][0], 0, 0, 0);
        acc[0][1] = __builtin_amdgcn_mfma_f32_16x16x32_bf16(a0, bv1, acc[0][1], 0, 0, 0);
        acc[1][0] = __builtin_amdgcn_mfma_f32_16x16x32_bf16(a1, bv0, acc[1][0], 0, 0, 0);
        acc[1][1] = __builtin_amdgcn_mfma_f32_16x16x32_bf16(a1, bv1, acc[1][1], 0, 0, 0);
        if (tt + 1 < NL) {
            writeLDS((tt + 1) & 1);
            __syncthreads();
        }
    }

    const float* bias = b0;
    if (MODE == 1) {
        int sel = colbase >> 8;
        bias = sel == 0 ? b0 : (sel == 1 ? b1 : b2);
    }
    int colq = (colbase & 255);
    float* Cp = (MODE == 0) ? C + (size_t)blockIdx.z * pstride : C;
    #pragma unroll
    for (int fr = 0; fr < 2; ++fr) {
        #pragma unroll
        for (int fc = 0; fc < 2; ++fc) {
            int coll = wc + fc * 16 + (lane & 15);
            int col = colbase + coll;
            #pragma unroll
            for (int i = 0; i < 4; ++i) {
                int row = rowbase + wr + fr * 16 + (lane >> 4) * 4 + i;
                float v = acc[fr][fc][i];
                if (MODE == 0) {
                    Cp[(size_t)row * ldc + col] = v;
                } else if (MODE == 1) {
                    Cb[(size_t)row * ldc + col] = f2b(v + bias[colq + coll]);
                } else {
                    v += bias[col];
                    v = 0.5f * v * (1.0f + erff(v * 0.70710678118654752f));
                    Cb[(size_t)row * ldc + col] = f2b(v);
                }
            }
        }
    }
}

// ---------------------------------------------------------------- attention: bf16 K/V, double-buffered LDS tiles
__global__ __launch_bounds__(256) void attn_kernel(const unsigned short* __restrict__ QKV,
                                                   const int* __restrict__ idx_j,
                                                   const float* __restrict__ d_ij,
                                                   const void* __restrict__ mask,
                                                   const float* __restrict__ shifts,
                                                   const float* __restrict__ Wrb,
                                                   const float* __restrict__ brb,
                                                   const int* __restrict__ flag,
                                                   unsigned short* __restrict__ Ub) {
    __shared__ unsigned short Kt[2][16][280];
    __shared__ float rad[Mm][36];
    __shared__ float att[Hh][Mm];
    __shared__ float attbar[Mm];
    __shared__ int   jl[Mm];
    __shared__ float dv[Mm];
    __shared__ int   maskf[Mm];
    __shared__ float shs[Rr];

    int row = blockIdx.x;
    int b = row >> 9;
    int tid = threadIdx.x;
    bool boolmask = (*flag != 0);

    if (tid < Mm) jl[tid] = idx_j[row * Mm + tid];
    else if (tid < 128) { int m = tid - 64; dv[m] = d_ij[row * Mm + m]; }
    else if (tid < 160) shs[tid - 128] = shifts[tid - 128];
    else if (tid >= 192) {
        int m = tid - 192;
        maskf[m] = boolmask ? (int)((const unsigned char*)mask)[row * Mm + m]
                            : ((const int*)mask)[row * Mm + m];
    }

    int half = tid & 1;
    int p = tid >> 1;
    int hh = p >> 4;
    int ml = p & 15;
    float qf[16];
    {
        const unsigned short* qrow = QKV + (size_t)row * 768 + hh * 32 + half * 16;
        ushort8 q0 = *reinterpret_cast<const ushort8*>(qrow);
        ushort8 q1 = *reinterpret_cast<const ushort8*>(qrow + 8);
        #pragma unroll
        for (int i = 0; i < 8; ++i) { qf[i] = b2f(q0[i]); qf[8 + i] = b2f(q1[i]); }
    }
    float4 wreg[4];
    #pragma unroll
    for (int c = 0; c < 4; ++c)
        wreg[c] = *reinterpret_cast<const float4*>(Wrb + hh * Rr + half * 16 + c * 4);
    float brbh = brb[hh];
    __syncthreads();

    auto stage = [&](int t, int seg, int buf) {
        #pragma unroll
        for (int q = 0; q < 2; ++q) {
            int chunk = q * 256 + tid;
            int r = chunk >> 5, s = chunk & 31;
            int j = jl[t * 16 + r];
            const uint4* src = reinterpret_cast<const uint4*>(QKV + (size_t)(b * Nn + j) * 768 + seg);
            uint4 v = src[s];
            *reinterpret_cast<uint4*>(&Kt[buf][r][s * 8]) = v;
        }
    };

    #pragma unroll
    for (int it = 0; it < 8; ++it) {
        int i = tid + it * 256;
        int m = i >> 5, r = i & 31;
        float t = dv[m] - shs[r];
        rad[m][r] = expf(-4.0f * t * t);
    }
    stage(0, 256, 0);
    __syncthreads();

    for (int t = 0; t < 4; ++t) {
        if (t < 3) stage(t + 1, 256, (t + 1) & 1);
        int buf = t & 1;
        const unsigned short* kr = &Kt[buf][ml][hh * 32 + half * 16];
        ushort8 k0 = *reinterpret_cast<const ushort8*>(kr);
        ushort8 k1 = *reinterpret_cast<const ushort8*>(kr + 8);
        float accK = 0.f;
        #pragma unroll
        for (int i = 0; i < 8; ++i) accK = fmaf(qf[i], b2f(k0[i]), accK);
        #pragma unroll
        for (int i = 0; i < 8; ++i) accK = fmaf(qf[8 + i], b2f(k1[i]), accK);
        float accR = 0.f;
        #pragma unroll
        for (int c = 0; c < 4; ++c) {
            float4 rv = *reinterpret_cast<const float4*>(&rad[t * 16 + ml][half * 16 + c * 4]);
            accR += wreg[c].x * rv.x + wreg[c].y * rv.y + wreg[c].z * rv.z + wreg[c].w * rv.w;
        }
        float tv = accK * 0.17677669529663687f + accR;
        tv += __shfl_xor(tv, 1);
        if (!half) {
            int m = t * 16 + ml;
            att[hh][m] = maskf[m] ? -INFINITY : (tv + brbh);
        }
        __syncthreads();
    }

    {
        int h = tid >> 5, l = tid & 31;
        float s0 = att[h][l], s1 = att[h][l + 32];
        float mx = fmaxf(s0, s1);
        #pragma unroll
        for (int off = 16; off; off >>= 1) mx = fmaxf(mx, __shfl_xor(mx, off, 32));
        float e0 = 0.f, e1 = 0.f;
        if (mx != -INFINITY) {
            e0 = expf(s0 - mx);
            e1 = expf(s1 - mx);
        }
        float sm = e0 + e1;
        #pragma unroll
        for (int off = 16; off; off >>= 1) sm += __shfl_xor(sm, off, 32);
        float inv = sm > 0.f ? 1.f / sm : 0.f;
        att[h][l] = e0 * inv;
        att[h][l + 32] = e1 * inv;
    }
    stage(0, 512, 0);
    __syncthreads();

    float ctx = 0.f;
    int h2 = tid >> 5, d0 = tid & 31;
    for (int t = 0; t < 4; ++t) {
        if (t < 3) stage(t + 1, 512, (t + 1) & 1);
        int buf = t & 1;
        #pragma unroll
        for (int m = 0; m < 16; ++m)
            ctx = fmaf(att[h2][t * 16 + m], b2f(Kt[buf][m][h2 * 32 + d0]), ctx);
        if (t == 0 && tid < Mm) {
            float sv = 0.f;
            #pragma unroll
            for (int h = 0; h < Hh; ++h) sv += att[h][tid];
            attbar[tid] = sv * 0.125f;
        }
        __syncthreads();
    }

    Ub[(size_t)row * KOUT + Ff + tid] = f2b(ctx);

    if (tid < 64) {
        int g = tid >> 1;
        float acc = 0.f;
        #pragma unroll
        for (int i = 0; i < 32; ++i) {
            int m = half * 32 + i;
            acc = fmaf(attbar[m], rad[m][g], acc);
        }
        acc += __shfl_xor(acc, 1);
        if (!half) Ub[(size_t)row * KOUT + 2 * Ff + g] = f2b(acc);
    }
}

// ---------------------------------------------------------------- residual + bias + 2 partials + LN (wave per row)
template<int S, int WB>
__global__ __launch_bounds__(256) void add_ln_c(const float* __restrict__ x0,
                                                const float* __restrict__ part, size_t pstride,
                                                const float* __restrict__ bias,
                                                const float* __restrict__ g,
                                                const float* __restrict__ be,
                                                float* __restrict__ outp,
                                                unsigned short* __restrict__ xb) {
    int tid = threadIdx.x;
    int wave = tid >> 6, lane = tid & 63;
    int row = blockIdx.x * 4 + wave;
    size_t off = (size_t)row * Ff + lane * 4;
    float4 v = *reinterpret_cast<const float4*>(x0 + off);
    float4 bb = *reinterpret_cast<const float4*>(bias + lane * 4);
    v.x += bb.x; v.y += bb.y; v.z += bb.z; v.w += bb.w;
    #pragma unroll
    for (int s = 0; s < S; ++s) {
        float4 p = *reinterpret_cast<const float4*>(part + (size_t)s * pstride + off);
        v.x += p.x; v.y += p.y; v.z += p.z; v.w += p.w;
    }
    float sm = v.x + v.y + v.z + v.w;
    #pragma unroll
    for (int o = 32; o; o >>= 1) sm += __shfl_xor(sm, o, 64);
    float mu = sm * (1.f / Ff);
    float4 c = {v.x - mu, v.y - mu, v.z - mu, v.w - mu};
    float s2 = c.x * c.x + c.y * c.y + c.z * c.z + c.w * c.w;
    #pragma unroll
    for (int o = 32; o; o >>= 1) s2 += __shfl_xor(s2, o, 64);
    float inv = rsqrtf(s2 * (1.f / Ff) + 1e-5f);
    float4 gg = *reinterpret_cast<const float4*>(g + lane * 4);
    float4 ee = *reinterpret_cast<const float4*>(be + lane * 4);
    float4 r;
    r.x = c.x * inv * gg.x + ee.x;
    r.y = c.y * inv * gg.y + ee.y;
    r.z = c.z * inv * gg.z + ee.z;
    r.w = c.w * inv * gg.w + ee.w;
    *reinterpret_cast<float4*>(outp + off) = r;
    if (WB) {
        ushort4 u;
        u.x = f2b(r.x); u.y = f2b(r.y); u.z = f2b(r.z); u.w = f2b(r.w);
        *reinterpret_cast<ushort4*>(&xb[off]) = u;
    }
}

// ---------------------------------------------------------------- launch
extern "C" void kernel_launch(void* const* d_in, const int* in_sizes, int n_in,
                              void* d_out, int out_size, void* d_ws, size_t ws_size,
                              hipStream_t stream) {
    const float* a       = (const float*)d_in[0];
    const float* charges = (const float*)d_in[1];
    const int*   idx_j   = (const int*)  d_in[2];
    const float* d_ij    = (const float*)d_in[3];
    const void*  mask    =               d_in[4];
    const float* shifts  = (const float*)d_in[5];
    const float* Wq   = (const float*)d_in[6];  const float* bq   = (const float*)d_in[7];
    const float* Wk   = (const float*)d_in[8];  const float* bk   = (const float*)d_in[9];
    const float* Wv   = (const float*)d_in[10]; const float* bv   = (const float*)d_in[11];
    const float* Wrb  = (const float*)d_in[12]; const float* brb  = (const float*)d_in[13];
    const float* Wout = (const float*)d_in[14]; const float* bout = (const float*)d_in[15];
    const float* g1   = (const float*)d_in[16]; const float* b1   = (const float*)d_in[17];
    const float* g2   = (const float*)d_in[18]; const float* b2   = (const float*)d_in[19];
    const float* Wf1  = (const float*)d_in[20]; const float* bf1  = (const float*)d_in[21];
    const float* Wf2  = (const float*)d_in[22]; const float* bf2  = (const float*)d_in[23];
    float* outp = (float*)d_out;

    float* ws   = (float*)d_ws;
    int*   flag = (int*)d_ws;
    // ws layout (floats): flag(1024) | part (1,048,576) | xbuf (524,288) | bf16 arena (5,472,256 ushorts)
    float* part = ws + 1024;
    float* xbuf = part + 1048576;
    unsigned short* arena = (unsigned short*)(xbuf + 524288);
    unsigned short* centerb = arena + OFF_CENTER;
    unsigned short* Wqkvb   = arena + OFF_WQKV;
    unsigned short* Woutb   = arena + OFF_WOUT;
    unsigned short* Wf1b    = arena + OFF_WF1;
    unsigned short* Wf2b    = arena + OFF_WF2;
    unsigned short* Ub      = arena + OFF_U;
    unsigned short* xb      = arena + OFF_XB;
    unsigned short* ffhb    = arena + OFF_FFH;
    unsigned short* QKVB16  = arena + OFF_QKVB;

    hipMemsetAsync(flag, 0, sizeof(int), stream);
    prep<<<CONV_BLK4 + A2U_BLK4 + MSK_BLK16, 256, 0, stream>>>(
        a, charges, Wq, Wk, Wv, Wout, Wf1, Wf2, (const unsigned char*)mask, flag, arena);

    // QKV: [2048 x 768], K=288 (9 tiles), bias fused, bf16 out
    gemm_mfma<9, 1, 1><<<dim3(12, 32, 1), 256, 0, stream>>>(
        centerb, KINP, Wqkvb, KINP, bq, bk, bv, nullptr, QKVB16, 768, 0);

    attn_kernel<<<ROWS, 256, 0, stream>>>(QKVB16, idx_j, d_ij, mask, shifts, Wrb, brb, flag, Ub);

    // Wout: [2048 x 256], K=544 (17 tiles), split 2
    gemm_mfma<17, 2, 0><<<dim3(4, 32, 2), 256, 0, stream>>>(
        Ub, KOUT, Woutb, KOUT, nullptr, nullptr, nullptr, part, nullptr, Ff, (size_t)ROWS * Ff);
    add_ln_c<2, 1><<<ROWS / 4, 256, 0, stream>>>(a, part, (size_t)ROWS * Ff, bout, g1, b1, xbuf, xb);

    // FFN1: [2048 x 512], K=256 (8 tiles), GELU+bias epilogue -> bf16
    gemm_mfma<8, 1, 2><<<dim3(8, 32, 1), 256, 0, stream>>>(
        xb, Ff, Wf1b, Ff, bf1, nullptr, nullptr, nullptr, ffhb, FFNH, 0);

    // FFN2: [2048 x 256], K=512 (16 tiles), split 2
    gemm_mfma<16, 2, 0><<<dim3(4, 32, 2), 256, 0, stream>>>(
        ffhb, FFNH, Wf2b, FFNH, nullptr, nullptr, nullptr, part, nullptr, Ff, (size_t)ROWS * Ff);
    add_ln_c<2, 0><<<ROWS / 4, 256, 0, stream>>>(xbuf, part, (size_t)ROWS * Ff, bf2, g2, b2, outp, nullptr);
}